// Round 4
// baseline (236.985 us; speedup 1.0000x reference)
//
#include <hip/hip_runtime.h>

#define NB 64        // bins
#define HW 65536     // pixels per channel (256*256)
#define NCH 24       // B*C = 8*3
#define SPLIT 32     // segments per channel-image
#define RAD 5        // truncation radius in bins: weights beyond |u|>5.5 < 2e-7
#define PAD 76       // per-wave padded histogram: indices 0..73 used, 76 for align

// Soft-histogram weight: w_j(x) = exp(-2048*(x - j/63)^2) = exp(-K*(f-j)^2),
// f = 63x, K = 2048/3969 (sigma ~= 0.98 bins). Only bins with |f-j| <= 5.5
// matter (tail < 1.7e-7 each, total tail mass ~1.4e-7 relative). Each pixel
// scatters 11 weights into a per-wave LDS histogram with +-RAD guard zones;
// guard entries (bins < 0 or > 63) are discarded at the end, matching the
// reference (those bins don't exist there).
__global__ __launch_bounds__(256) void chml_hist(const float* __restrict__ pred,
                                                 const float* __restrict__ targ,
                                                 float* __restrict__ part) {
  const int seg = blockIdx.x;   // 0..SPLIT-1
  const int ct  = blockIdx.y;   // 0..2*NCH-1
  const float* src = (ct < NCH) ? (pred + (size_t)ct * HW)
                                : (targ + (size_t)(ct - NCH) * HW);
  const int tid  = threadIdx.x;
  const int wave = tid >> 6;

  __shared__ float h[4][PAD];
  for (int i = tid; i < 4 * PAD; i += 256) ((float*)h)[i] = 0.0f;
  __syncthreads();

  const float K = 0.51599899f;  // 2048/3969
  float* hw = h[wave];

  // segment = 2048 elems = 512 float4; 256 threads x 2 iterations, coalesced
  const float4* s4 = (const float4*)(src + (size_t)seg * (HW / SPLIT));
#pragma unroll
  for (int k = 0; k < (HW / SPLIT) / (4 * 256); ++k) {
    float4 p = s4[k * 256 + tid];
    float fe[4] = {p.x * 63.0f, p.y * 63.0f, p.z * 63.0f, p.w * 63.0f};
#pragma unroll
    for (int e = 0; e < 4; ++e) {
      float n = rintf(fe[e]);      // nearest bin, 0..63
      float d = fe[e] - n;         // residual in [-0.5, 0.5]
      int   ni = (int)n;
#pragma unroll
      for (int r = -RAD; r <= RAD; ++r) {
        float u = d - (float)r;    // = f - (ni + r)
        float w = __expf(u * u * -K);
        atomicAdd(&hw[ni + r + RAD], w);   // index in [0, 73]
      }
    }
  }

  __syncthreads();
  if (tid < NB) {
    // real bin j lives at padded index j + RAD; guard zones discarded
    float v = (h[0][tid + RAD] + h[1][tid + RAD]) +
              (h[2][tid + RAD] + h[3][tid + RAD]);
    part[((size_t)ct * SPLIT + seg) * NB + tid] = v;
  }
}

// Kernel B: sum segment partials, normalize, cumsum, mean |diff|.
// 1 block, 8 waves; lane = bin.
__global__ __launch_bounds__(512) void chml_finish(const float* __restrict__ part,
                                                   float* __restrict__ out) {
  const int tid  = threadIdx.x;
  const int lane = tid & 63;
  const int wave = tid >> 6;  // 0..7
  float lsum = 0.0f;
  for (int c = wave; c < NCH; c += 8) {
    float vp = 0.0f, vt = 0.0f;
#pragma unroll
    for (int s = 0; s < SPLIT; ++s) {
      vp += part[((size_t)c * SPLIT + s) * NB + lane];
      vt += part[((size_t)(c + NCH) * SPLIT + s) * NB + lane];
    }
    // inclusive prefix scan across 64 lanes (Hillis-Steele)
#pragma unroll
    for (int off = 1; off < 64; off <<= 1) {
      float up = __shfl_up(vp, off, 64);
      float ut = __shfl_up(vt, off, 64);
      if (lane >= off) { vp += up; vt += ut; }
    }
    float totp = __shfl(vp, 63, 64);
    float tott = __shfl(vt, 63, 64);
    lsum += fabsf(vp / (totp + 1e-7f) - vt / (tott + 1e-7f));
  }
  // reduce loss over lanes
#pragma unroll
  for (int off = 32; off >= 1; off >>= 1) lsum += __shfl_xor(lsum, off, 64);
  __shared__ float red[8];
  if (lane == 0) red[wave] = lsum;
  __syncthreads();
  if (tid == 0) {
    float t = (red[0] + red[1]) + (red[2] + red[3]) +
              (red[4] + red[5]) + (red[6] + red[7]);
    out[0] = t * (1.0f / (float)(NCH * NB));
  }
}

extern "C" void kernel_launch(void* const* d_in, const int* in_sizes, int n_in,
                              void* d_out, int out_size, void* d_ws, size_t ws_size,
                              hipStream_t stream) {
  const float* pred = (const float*)d_in[0];
  const float* targ = (const float*)d_in[1];
  float* part = (float*)d_ws;  // 2*NCH*SPLIT*NB floats = 384 KB

  dim3 grid(SPLIT, 2 * NCH);
  chml_hist<<<grid, 256, 0, stream>>>(pred, targ, part);
  chml_finish<<<1, 512, 0, stream>>>(part, (float*)d_out);
}

// Round 5
// 80.624 us; speedup vs baseline: 2.9394x; 2.9394x over previous
//
#include <hip/hip_runtime.h>

#define NB 64        // bins
#define HW 65536     // pixels per channel (256*256)
#define NCH 24       // B*C = 8*3
#define SPLIT 32     // segments per channel-image
#define RAD 5        // truncation radius: dropped mass < 1.5e-7 relative
#define NSLOT 74     // padded bins: slot = bin + RAD, bin in [-5, 68]

// w_j(x) = exp(-2048*(x - j/63)^2) = exp(-K*(f-j)^2), f = 63x, K = 2048/3969.
// For j = ni + r (ni = round(f), d = f - ni):
//   w = exp(-K*(d-r)^2) = w0 * (e^{2Kd})^r * C_r,  w0 = e^{-K d^2}, C_r = e^{-K r^2}
// -> 3 transcendentals per pixel, 11 taps (|r| <= 5).
// Accumulation: per-THREAD private LDS columns h[slot][tid] — no atomics,
// bank = tid%32 (uniform 2-way = free). Per pixel: 11 reads batched, then
// 11 writes (DS completes in order per wave -> RMW is race- and stall-safe).
__global__ __launch_bounds__(256) void chml_hist(const float* __restrict__ pred,
                                                 const float* __restrict__ targ,
                                                 float* __restrict__ part) {
  const int seg = blockIdx.x;   // 0..SPLIT-1
  const int ct  = blockIdx.y;   // 0..2*NCH-1
  const float* src = (ct < NCH) ? (pred + (size_t)ct * HW)
                                : (targ + (size_t)(ct - NCH) * HW);
  const int tid = threadIdx.x;

  __shared__ float h[NSLOT][256];
  {
    float4* hz = (float4*)&h[0][0];
#pragma unroll 2
    for (int i = tid; i < NSLOT * 256 / 4; i += 256)
      hz[i] = make_float4(0.f, 0.f, 0.f, 0.f);
  }
  __syncthreads();

  const float K  = 0.51599899f;  // 2048/3969
  const float C1 = 5.96905619e-01f;  // exp(-K*1)
  const float C2 = 1.26927917e-01f;  // exp(-K*4)
  const float C3 = 9.61165782e-03f;  // exp(-K*9)
  const float C4 = 2.59240329e-04f;  // exp(-K*16)
  const float C5 = 2.49029640e-06f;  // exp(-K*25)

  // segment = 2048 elems = 512 float4; 256 threads x 2 iterations, coalesced
  const float4* s4 = (const float4*)(src + (size_t)seg * (HW / SPLIT));
#pragma unroll
  for (int k = 0; k < (HW / SPLIT) / (4 * 256); ++k) {
    float4 p = s4[k * 256 + tid];
    float pe[4] = {p.x, p.y, p.z, p.w};
#pragma unroll
    for (int e = 0; e < 4; ++e) {
      float f = pe[e] * 63.0f;
      float n = rintf(f);
      float d = f - n;            // [-0.5, 0.5]
      int  ni = (int)n;           // 0..63
      float w0 = __expf(d * d * -K);
      float mp = __expf(d * (2.0f * K));   // e^{+2Kd}
      float mn = __expf(d * (-2.0f * K));  // e^{-2Kd}
      float mp2 = mp * mp, mp3 = mp2 * mp, mp4 = mp2 * mp2, mp5 = mp4 * mp;
      float mn2 = mn * mn, mn3 = mn2 * mn, mn4 = mn2 * mn2, mn5 = mn4 * mn;
      float A1 = w0 * C1, A2 = w0 * C2, A3 = w0 * C3, A4 = w0 * C4, A5 = w0 * C5;
      float w[11];
      w[0]  = A5 * mn5;  // r = -5
      w[1]  = A4 * mn4;
      w[2]  = A3 * mn3;
      w[3]  = A2 * mn2;
      w[4]  = A1 * mn;
      w[5]  = w0;        // r = 0
      w[6]  = A1 * mp;
      w[7]  = A2 * mp2;
      w[8]  = A3 * mp3;
      w[9]  = A4 * mp4;
      w[10] = A5 * mp5;  // r = +5
      float* col = &h[ni][tid];  // slot (ni + r + RAD) = base + (r+RAD)*256
      float t[11];
#pragma unroll
      for (int j = 0; j < 11; ++j) t[j] = col[j * 256];
#pragma unroll
      for (int j = 0; j < 11; ++j) col[j * 256] = t[j] + w[j];
    }
  }
  __syncthreads();

  // Fold 256 columns -> 1 for the 64 real bins (slots RAD..RAD+63).
#pragma unroll
  for (int st = 128; st >= 1; st >>= 1) {
    for (int idx = tid; idx < NB * st; idx += 256) {
      int s = idx / st, c = idx % st;   // st is pow2 after unroll -> shifts
      h[s + RAD][c] += h[s + RAD][c + st];
    }
    __syncthreads();
  }
  if (tid < NB)
    part[((size_t)ct * SPLIT + seg) * NB + tid] = h[tid + RAD][0];
}

// Per-channel: sum segment partials, normalize, cumsum, sum |cdf diff|.
// 24 blocks x 64 threads; lane = bin. Writes chanloss[c].
__global__ __launch_bounds__(64) void chml_chan(const float* __restrict__ part,
                                                float* __restrict__ chanloss) {
  const int c    = blockIdx.x;
  const int lane = threadIdx.x;
  float vp = 0.0f, vt = 0.0f;
#pragma unroll
  for (int s = 0; s < SPLIT; ++s) {
    vp += part[((size_t)c * SPLIT + s) * NB + lane];
    vt += part[((size_t)(c + NCH) * SPLIT + s) * NB + lane];
  }
  // inclusive prefix scan across 64 lanes
#pragma unroll
  for (int off = 1; off < 64; off <<= 1) {
    float up = __shfl_up(vp, off, 64);
    float ut = __shfl_up(vt, off, 64);
    if (lane >= off) { vp += up; vt += ut; }
  }
  float totp = __shfl(vp, 63, 64);
  float tott = __shfl(vt, 63, 64);
  float l = fabsf(vp / (totp + 1e-7f) - vt / (tott + 1e-7f));
#pragma unroll
  for (int off = 32; off >= 1; off >>= 1) l += __shfl_xor(l, off, 64);
  if (lane == 0) chanloss[c] = l;
}

// Final: mean over 24*64 terms.
__global__ __launch_bounds__(64) void chml_final(const float* __restrict__ chanloss,
                                                 float* __restrict__ out) {
  const int lane = threadIdx.x;
  float l = (lane < NCH) ? chanloss[lane] : 0.0f;
#pragma unroll
  for (int off = 32; off >= 1; off >>= 1) l += __shfl_xor(l, off, 64);
  if (lane == 0) out[0] = l * (1.0f / (float)(NCH * NB));
}

extern "C" void kernel_launch(void* const* d_in, const int* in_sizes, int n_in,
                              void* d_out, int out_size, void* d_ws, size_t ws_size,
                              hipStream_t stream) {
  const float* pred = (const float*)d_in[0];
  const float* targ = (const float*)d_in[1];
  float* part     = (float*)d_ws;                       // 48*32*64 floats = 384 KB
  float* chanloss = part + (size_t)2 * NCH * SPLIT * NB; // +24 floats

  dim3 grid(SPLIT, 2 * NCH);
  chml_hist<<<grid, 256, 0, stream>>>(pred, targ, part);
  chml_chan<<<NCH, 64, 0, stream>>>(part, chanloss);
  chml_final<<<1, 64, 0, stream>>>(chanloss, (float*)d_out);
}